// Round 5
// baseline (460.304 us; speedup 1.0000x reference)
//
#include <hip/hip_runtime.h>

#define N_NODES 100000
#define N_EDGES 3200000
#define D_FEAT 256
#define HIDDEN 16
#define OUT 256
#define N_TILES 1563          // ceil(N_NODES/64); last tile has 32 valid rows
#define G_HAGG 6250           // N_NODES*16/256
#define EDGE_BLOCKS 50000     // N_EDGES*4/256

typedef __attribute__((ext_vector_type(8))) _Float16 half8;
typedef __attribute__((ext_vector_type(4))) float f32x4;

__device__ __forceinline__ unsigned umax32(unsigned a, unsigned b) { return a > b ? a : b; }

// Monotone f16-bits <-> u16 mapping: encoded compare == float compare (no NaNs here).
__device__ __forceinline__ unsigned short enc16(unsigned short u) {
    return (u & 0x8000) ? (unsigned short)~u : (unsigned short)(u | 0x8000);
}
__device__ __forceinline__ _Float16 dec16(unsigned short e) {
    if (e == 0) return (_Float16)0.f;   // sentinel: no in-edge -> 0
    unsigned short b = (e & 0x8000) ? (unsigned short)(e & 0x7FFF) : (unsigned short)~e;
    return __builtin_bit_cast(_Float16, b);
}

// per-u16 max of 4 lanes packed in u64
__device__ __forceinline__ unsigned long long pmax16x4(unsigned long long a, unsigned long long b) {
    unsigned a0 = (unsigned)a, a1 = (unsigned)(a >> 32);
    unsigned b0 = (unsigned)b, b1 = (unsigned)(b >> 32);
    unsigned r0 = umax32(a0 & 0xFFFFu, b0 & 0xFFFFu) | (umax32(a0 >> 16, b0 >> 16) << 16);
    unsigned r1 = umax32(a1 & 0xFFFFu, b1 & 0xFFFFu) | (umax32(a1 >> 16, b1 >> 16) << 16);
    return (unsigned long long)r0 | ((unsigned long long)r1 << 32);
}

// Kernel 1: h_agg = x @ W_agg + b_agg (fp32 accum) -> packed-encoded hpk,
// zeroed aenc, x cast to f16 (xh). Extra blocks (>= G_HAGG) pack Wp / Wnp.
__global__ __launch_bounds__(256) void k_hagg(
    const float* __restrict__ x, const float* __restrict__ W_agg,
    const float* __restrict__ b_agg, unsigned* __restrict__ hpk,
    unsigned* __restrict__ aenc, _Float16* __restrict__ xh,
    const float* __restrict__ Wn, const float* __restrict__ Wng,
    _Float16* __restrict__ Wp, _Float16* __restrict__ Wnp)
{
    int t = threadIdx.x;
    if (blockIdx.x >= G_HAGG) {
        // ---- weight-packing path (36 blocks: 8192 Wp items + 1024 Wnp items)
        int id = (blockIdx.x - G_HAGG) * 256 + t;
        if (id < 16 * 8 * 64) {
            int l = id & 63, kb = (id >> 6) & 7, nb = id >> 9;
            int col = nb * 16 + (l & 15);
            int k0 = kb * 32 + (l >> 4) * 8;
            half8 v;
            #pragma unroll
            for (int j = 0; j < 8; ++j) v[j] = (_Float16)Wn[(size_t)(k0 + j) * OUT + col];
            ((half8*)Wp)[id] = v;
        } else {
            int id2 = id - 16 * 8 * 64;
            int l = id2 & 63, nb = id2 >> 6;
            int col = nb * 16 + (l & 15);
            int k0 = (l >> 4) * 8;
            half8 v;
            #pragma unroll
            for (int j = 0; j < 8; ++j) {
                int k = k0 + j;
                v[j] = (k < HIDDEN) ? (_Float16)Wng[(size_t)k * OUT + col] : (_Float16)0.f;
            }
            ((half8*)Wnp)[id2] = v;
        }
        return;
    }

    __shared__ float WlT[HIDDEN * 260];   // [k][d], row stride 260 floats
    for (int i = t; i < D_FEAT * HIDDEN; i += 256)
        WlT[(i & 15) * 260 + (i >> 4)] = W_agg[i];
    __syncthreads();

    int gid = blockIdx.x * 256 + t;
    int node = gid >> 4, k = gid & 15;

    const float4* x4 = (const float4*)(x + (size_t)node * D_FEAT);
    const float4* wt4 = (const float4*)(WlT + k * 260);
    float acc = b_agg[k];
    #pragma unroll 8
    for (int dv = 0; dv < D_FEAT / 4; ++dv) {
        float4 xv = x4[dv];
        float4 wv = wt4[dv];
        acc = fmaf(xv.x, wv.x, acc);
        acc = fmaf(xv.y, wv.y, acc);
        acc = fmaf(xv.z, wv.z, acc);
        acc = fmaf(xv.w, wv.w, acc);
    }

    unsigned short e16 = enc16(__builtin_bit_cast(unsigned short, (_Float16)acc));
    unsigned other = (unsigned)__shfl_xor((int)e16, 1);
    if ((k & 1) == 0) {
        unsigned word = (unsigned)e16 | (other << 16);
        size_t idx = (size_t)node * 8 + (k >> 1);
        hpk[idx] = word;
        aenc[idx] = 0u;
    }

    // f16 conversion of this thread's 16-element slice of the row (L1-hot).
    const float4* xr4 = x4 + k * 4;
    float4 c0 = xr4[0], c1 = xr4[1], c2 = xr4[2], c3 = xr4[3];
    half8 lo, hi;
    lo[0]=(_Float16)c0.x; lo[1]=(_Float16)c0.y; lo[2]=(_Float16)c0.z; lo[3]=(_Float16)c0.w;
    lo[4]=(_Float16)c1.x; lo[5]=(_Float16)c1.y; lo[6]=(_Float16)c1.z; lo[7]=(_Float16)c1.w;
    hi[0]=(_Float16)c2.x; hi[1]=(_Float16)c2.y; hi[2]=(_Float16)c2.z; hi[3]=(_Float16)c2.w;
    hi[4]=(_Float16)c3.x; hi[5]=(_Float16)c3.y; hi[6]=(_Float16)c3.z; hi[7]=(_Float16)c3.w;
    half8* xo = (half8*)(xh + (size_t)node * D_FEAT + k * 16);
    xo[0] = lo; xo[1] = hi;
}

// Kernel A (fused): blocks [0, N_TILES) = node-GEMM tiles writing packed-f16 h;
// blocks [N_TILES, ...) = edge segment-max (u64 CAS, 4 lanes/edge).
// The two tasks are fully independent -> dispatch order irrelevant for correctness.
__global__ __launch_bounds__(256) void k_fused(
    const _Float16* __restrict__ xh, const _Float16* __restrict__ Wp,
    const float* __restrict__ b_node,
    const int* __restrict__ src, const int* __restrict__ dst,
    const unsigned long long* __restrict__ hpk64,
    unsigned long long* __restrict__ aenc64,
    _Float16* __restrict__ hlast, float* __restrict__ out)
{
    int t = threadIdx.x;
    if (blockIdx.x >= N_TILES) {
        // ---- edge path: one shot, 4 lanes per edge, u64 packed CAS-max
        int tid = (blockIdx.x - N_TILES) * 256 + t;
        int e = tid >> 2, p = tid & 3;
        int s = __builtin_nontemporal_load(src + e);
        int d = __builtin_nontemporal_load(dst + e);
        unsigned long long mine = hpk64[(size_t)s * 4 + p];
        unsigned long long* addr = aenc64 + (size_t)d * 4 + p;
        unsigned long long cur = *addr;
        unsigned long long nv = pmax16x4(cur, mine);
        while (nv != cur) {
            unsigned long long old = atomicCAS(addr, cur, nv);
            if (old == cur) break;
            cur = old;
            nv = pmax16x4(cur, mine);
        }
        return;
    }

    // ---- GEMM tile path: h = xh @ W_node + b_node for 64 nodes, store f16
    int tile = blockIdx.x;
    int base = tile * 64;
    int w = t >> 6, l = t & 63, lr = l & 15, lg = l >> 4;

    f32x4 acc[4][4];
    #pragma unroll
    for (int mb = 0; mb < 4; ++mb)
        #pragma unroll
        for (int nb = 0; nb < 4; ++nb) acc[mb][nb] = (f32x4){0.f, 0.f, 0.f, 0.f};

    size_t arow[4];
    #pragma unroll
    for (int mb = 0; mb < 4; ++mb) {
        int node = base + mb * 16 + lr;
        if (node > N_NODES - 1) node = N_NODES - 1;
        arow[mb] = (size_t)node * D_FEAT + lg * 8;
    }

    const half8* WpV = (const half8*)Wp;
    #pragma unroll
    for (int kb = 0; kb < 8; ++kb) {
        half8 a[4], b[4];
        #pragma unroll
        for (int mb = 0; mb < 4; ++mb)
            a[mb] = __builtin_nontemporal_load((const half8*)(xh + arow[mb] + kb * 32));
        #pragma unroll
        for (int nb = 0; nb < 4; ++nb)
            b[nb] = WpV[((w * 4 + nb) * 8 + kb) * 64 + l];
        #pragma unroll
        for (int mb = 0; mb < 4; ++mb)
            #pragma unroll
            for (int nb = 0; nb < 4; ++nb)
                acc[mb][nb] = __builtin_amdgcn_mfma_f32_16x16x32_f16(
                    a[mb], b[nb], acc[mb][nb], 0, 0, 0);
    }

    float bnc[4];
    #pragma unroll
    for (int nb = 0; nb < 4; ++nb) bnc[nb] = b_node[w * 64 + nb * 16 + lr];

    // pack this thread's 64 h values (order [mb][nb][r]) and store 128 B
    half8 hv8[8];
    #pragma unroll
    for (int mb = 0; mb < 4; ++mb)
        #pragma unroll
        for (int nb = 0; nb < 4; ++nb)
            #pragma unroll
            for (int r = 0; r < 4; ++r) {
                int idx = mb * 16 + nb * 4 + r;
                hv8[idx >> 3][idx & 7] = (_Float16)(acc[mb][nb][r] + bnc[nb]);
            }

    char* hb;
    if (tile == N_TILES - 1) hb = (char*)hlast + (size_t)t * 128;
    else hb = (char*)out + (size_t)(base + (t >> 2)) * 2048 + 1024 + (size_t)(t & 3) * 128;
    #pragma unroll
    for (int i = 0; i < 8; ++i)
        __builtin_nontemporal_store(hv8[i], (half8*)hb + i);
}

// Kernel 3 (epilogue): load packed h, neighbour MFMA from aenc, l2-normalize, store.
__global__ __launch_bounds__(256) void k_epi(
    const unsigned* __restrict__ aenc, const _Float16* __restrict__ Wnp,
    const float* __restrict__ b_neigh, const _Float16* __restrict__ hlast,
    float* __restrict__ out)
{
    __shared__ _Float16 aggL[64][40];
    __shared__ float ss[4][64];
    __shared__ float invl[64];

    int t = threadIdx.x;
    int w = t >> 6, l = t & 63, lr = l & 15, lg = l >> 4;
    int tile = blockIdx.x;
    int base = tile * 64;

    // stage + decode agg tile
    for (int i = t; i < 64 * 8; i += 256) {
        int nl = i >> 3, p = i & 7;
        int gn = base + nl;
        unsigned v = (gn < N_NODES) ? aenc[(size_t)gn * 8 + p] : 0u;
        aggL[nl][2 * p]     = dec16((unsigned short)(v & 0xFFFFu));
        aggL[nl][2 * p + 1] = dec16((unsigned short)(v >> 16));
    }
    for (int i = t; i < 64 * 16; i += 256)
        aggL[i >> 4][16 + (i & 15)] = (_Float16)0.f;

    // load this thread's packed h (written by k_fused thread t of same tile)
    const char* hb;
    if (tile == N_TILES - 1) hb = (const char*)hlast + (size_t)t * 128;
    else hb = (const char*)out + (size_t)(base + (t >> 2)) * 2048 + 1024 + (size_t)(t & 3) * 128;
    half8 hv8[8];
    #pragma unroll
    for (int i = 0; i < 8; ++i)
        hv8[i] = __builtin_nontemporal_load((const half8*)hb + i);

    __syncthreads();

    // neighbour layer: one MFMA per (mb,nb), K=32 (upper 16 zero-padded)
    f32x4 nacc[4][4];
    {
        half8 an[4], bn[4];
        #pragma unroll
        for (int mb = 0; mb < 4; ++mb)
            an[mb] = *(const half8*)(&aggL[mb * 16 + lr][lg * 8]);
        #pragma unroll
        for (int nb = 0; nb < 4; ++nb)
            bn[nb] = ((const half8*)Wnp)[(w * 4 + nb) * 64 + l];
        f32x4 z = (f32x4){0.f, 0.f, 0.f, 0.f};
        #pragma unroll
        for (int mb = 0; mb < 4; ++mb)
            #pragma unroll
            for (int nb = 0; nb < 4; ++nb)
                nacc[mb][nb] = __builtin_amdgcn_mfma_f32_16x16x32_f16(
                    an[mb], bn[nb], z, 0, 0, 0);
    }

    float bec[4];
    #pragma unroll
    for (int nb = 0; nb < 4; ++nb) bec[nb] = b_neigh[w * 64 + nb * 16 + lr];
    #pragma unroll
    for (int mb = 0; mb < 4; ++mb)
        #pragma unroll
        for (int nb = 0; nb < 4; ++nb)
            #pragma unroll
            for (int r = 0; r < 4; ++r)
                nacc[mb][nb][r] += bec[nb];

    // sum of squares per node row
    #pragma unroll
    for (int mb = 0; mb < 4; ++mb) {
        float p[4] = {0.f, 0.f, 0.f, 0.f};
        #pragma unroll
        for (int nb = 0; nb < 4; ++nb)
            #pragma unroll
            for (int r = 0; r < 4; ++r) {
                int idx = mb * 16 + nb * 4 + r;
                float hf = (float)hv8[idx >> 3][idx & 7];
                p[r] += hf * hf + nacc[mb][nb][r] * nacc[mb][nb][r];
            }
        #pragma unroll
        for (int r = 0; r < 4; ++r) {
            float v = p[r];
            v += __shfl_xor(v, 1);
            v += __shfl_xor(v, 2);
            v += __shfl_xor(v, 4);
            v += __shfl_xor(v, 8);
            if (lr == 0) ss[w][mb * 16 + lg * 4 + r] = v;
        }
    }
    __syncthreads();
    if (t < 64) {
        float sq = ss[0][t] + ss[1][t] + ss[2][t] + ss[3][t];
        invl[t] = rsqrtf(fmaxf(sq, 1e-12f));
    }
    __syncthreads();

    #pragma unroll
    for (int mb = 0; mb < 4; ++mb)
        #pragma unroll
        for (int r = 0; r < 4; ++r) {
            int slot = mb * 16 + lg * 4 + r;
            int node = base + slot;
            if (node < N_NODES) {
                float inv = invl[slot];
                size_t row = (size_t)node * (2 * OUT);
                #pragma unroll
                for (int nb = 0; nb < 4; ++nb) {
                    int col = w * 64 + nb * 16 + lr;
                    int idx = mb * 16 + nb * 4 + r;
                    out[row + col] = (float)hv8[idx >> 3][idx & 7] * inv;
                    out[row + OUT + col] = nacc[mb][nb][r] * inv;
                }
            }
        }
}

extern "C" void kernel_launch(void* const* d_in, const int* in_sizes, int n_in,
                              void* d_out, int out_size, void* d_ws, size_t ws_size,
                              hipStream_t stream) {
    const float* x       = (const float*)d_in[0];
    const int*   src     = (const int*)d_in[1];
    const int*   dst     = (const int*)d_in[2];
    const float* W_node  = (const float*)d_in[3];
    const float* b_node  = (const float*)d_in[4];
    const float* W_agg   = (const float*)d_in[5];
    const float* b_agg   = (const float*)d_in[6];
    const float* W_neigh = (const float*)d_in[7];
    const float* b_neigh = (const float*)d_in[8];
    float* out = (float*)d_out;

    char* ws = (char*)d_ws;
    unsigned*  hpk   = (unsigned*)ws;      ws += (size_t)N_NODES * 8 * 4;
    unsigned*  aenc  = (unsigned*)ws;      ws += (size_t)N_NODES * 8 * 4;
    _Float16*  xh    = (_Float16*)ws;      ws += (size_t)N_NODES * D_FEAT * 2;
    _Float16*  Wp    = (_Float16*)ws;      ws += (size_t)16 * 8 * 64 * 8 * 2;
    _Float16*  Wnp   = (_Float16*)ws;      ws += (size_t)16 * 64 * 8 * 2;
    _Float16*  hlast = (_Float16*)ws;      // 32 KB scratch for the ragged last tile

    k_hagg<<<G_HAGG + 36, 256, 0, stream>>>(x, W_agg, b_agg, hpk, aenc, xh,
                                            W_node, W_neigh, Wp, Wnp);

    k_fused<<<N_TILES + EDGE_BLOCKS, 256, 0, stream>>>(
        xh, Wp, b_node, src, dst,
        (const unsigned long long*)hpk, (unsigned long long*)aenc, hlast, out);

    k_epi<<<N_TILES, 256, 0, stream>>>(aenc, Wnp, b_neigh, hlast, out);
}

// Round 6
// 419.598 us; speedup vs baseline: 1.0970x; 1.0970x over previous
//
#include <hip/hip_runtime.h>

#define N_NODES 100000
#define N_EDGES 3200000
#define D_FEAT 256
#define HIDDEN 16
#define OUT 256
#define N_TILES 1563          // ceil(N_NODES/64)

typedef __attribute__((ext_vector_type(8))) _Float16 half8;
typedef __attribute__((ext_vector_type(4))) float f32x4;

__device__ __forceinline__ unsigned umax32(unsigned a, unsigned b) { return a > b ? a : b; }

// Monotone f16-bits <-> u16 mapping: encoded compare == float compare (no NaNs here).
__device__ __forceinline__ unsigned short enc16(unsigned short u) {
    return (u & 0x8000) ? (unsigned short)~u : (unsigned short)(u | 0x8000);
}
__device__ __forceinline__ _Float16 dec16(unsigned short e) {
    if (e == 0) return (_Float16)0.f;   // sentinel: no in-edge -> 0
    unsigned short b = (e & 0x8000) ? (unsigned short)(e & 0x7FFF) : (unsigned short)~e;
    return __builtin_bit_cast(_Float16, b);
}

// Pack W_node, W_neigh, W_agg into MFMA B-fragment layout (f16). 38 blocks.
__global__ void k_pack(const float* __restrict__ Wn, const float* __restrict__ Wng,
                       const float* __restrict__ Wag,
                       _Float16* __restrict__ Wp, _Float16* __restrict__ Wnp,
                       _Float16* __restrict__ Wap)
{
    int id = blockIdx.x * 256 + threadIdx.x;
    if (id < 8192) {                       // W_node: 16 nb x 8 kb x 64 lanes
        int l = id & 63, kb = (id >> 6) & 7, nb = id >> 9;
        int col = nb * 16 + (l & 15);
        int k0 = kb * 32 + (l >> 4) * 8;
        half8 v;
        #pragma unroll
        for (int j = 0; j < 8; ++j) v[j] = (_Float16)Wn[(size_t)(k0 + j) * OUT + col];
        ((half8*)Wp)[id] = v;
    } else if (id < 9216) {                // W_neigh: 16 nb x 64 lanes (K=32, zero-pad)
        int id2 = id - 8192;
        int l = id2 & 63, nb = id2 >> 6;
        int col = nb * 16 + (l & 15);
        int k0 = (l >> 4) * 8;
        half8 v;
        #pragma unroll
        for (int j = 0; j < 8; ++j) {
            int k = k0 + j;
            v[j] = (k < HIDDEN) ? (_Float16)Wng[(size_t)k * OUT + col] : (_Float16)0.f;
        }
        ((half8*)Wnp)[id2] = v;
    } else if (id < 9728) {                // W_agg: 1 nb (16 cols) x 8 kb x 64 lanes
        int id3 = id - 9216;
        int l = id3 & 63, kb = id3 >> 6;
        int col = l & 15;
        int k0 = kb * 32 + (l >> 4) * 8;
        half8 v;
        #pragma unroll
        for (int j = 0; j < 8; ++j) v[j] = (_Float16)Wag[(size_t)(k0 + j) * HIDDEN + col];
        ((half8*)Wap)[id3] = v;
    }
}

// K1: per 64-node tile, MFMA h = x@W_node (+bias, ->packed f16 hbuf) AND
// h_agg = x@W_agg (wave 0; +bias, encode -> hpk, zero aenc). x read once, f32,
// converted to f16 in registers.
__global__ __launch_bounds__(256) void k_gemm(
    const float* __restrict__ x, const _Float16* __restrict__ Wp,
    const _Float16* __restrict__ Wap, const float* __restrict__ b_node,
    const float* __restrict__ b_agg, unsigned* __restrict__ hpk,
    unsigned* __restrict__ aenc, _Float16* __restrict__ hbuf)
{
    __shared__ unsigned short eagg[64][18];

    int t = threadIdx.x;
    int w = t >> 6, l = t & 63, lr = l & 15, lg = l >> 4;
    int base = blockIdx.x * 64;

    size_t arow[4];
    #pragma unroll
    for (int mb = 0; mb < 4; ++mb) {
        int node = base + mb * 16 + lr;
        if (node > N_NODES - 1) node = N_NODES - 1;
        arow[mb] = (size_t)node * D_FEAT + lg * 8;
    }

    f32x4 acc[4][4];
    #pragma unroll
    for (int mb = 0; mb < 4; ++mb)
        #pragma unroll
        for (int nb = 0; nb < 4; ++nb) acc[mb][nb] = (f32x4){0.f, 0.f, 0.f, 0.f};
    f32x4 agga[4];
    #pragma unroll
    for (int mb = 0; mb < 4; ++mb) agga[mb] = (f32x4){0.f, 0.f, 0.f, 0.f};

    const half8* WpV = (const half8*)Wp;
    const half8* WaV = (const half8*)Wap;

    #pragma unroll
    for (int kb = 0; kb < 8; ++kb) {
        half8 a[4];
        #pragma unroll
        for (int mb = 0; mb < 4; ++mb) {
            const float4* p = (const float4*)(x + arow[mb] + kb * 32);
            float4 u = p[0], v = p[1];
            half8 h;
            h[0]=(_Float16)u.x; h[1]=(_Float16)u.y; h[2]=(_Float16)u.z; h[3]=(_Float16)u.w;
            h[4]=(_Float16)v.x; h[5]=(_Float16)v.y; h[6]=(_Float16)v.z; h[7]=(_Float16)v.w;
            a[mb] = h;
        }
        half8 b[4];
        #pragma unroll
        for (int nb = 0; nb < 4; ++nb)
            b[nb] = WpV[((w * 4 + nb) * 8 + kb) * 64 + l];
        if (w == 0) {
            half8 bg = WaV[kb * 64 + l];
            #pragma unroll
            for (int mb = 0; mb < 4; ++mb)
                agga[mb] = __builtin_amdgcn_mfma_f32_16x16x32_f16(a[mb], bg, agga[mb], 0, 0, 0);
        }
        #pragma unroll
        for (int mb = 0; mb < 4; ++mb)
            #pragma unroll
            for (int nb = 0; nb < 4; ++nb)
                acc[mb][nb] = __builtin_amdgcn_mfma_f32_16x16x32_f16(
                    a[mb], b[nb], acc[mb][nb], 0, 0, 0);
    }

    // wave 0: bias + encode h_agg into LDS (slot = node-in-tile, col = hidden idx)
    if (w == 0) {
        float ba = b_agg[lr];
        #pragma unroll
        for (int mb = 0; mb < 4; ++mb)
            #pragma unroll
            for (int r = 0; r < 4; ++r) {
                float val = agga[mb][r] + ba;
                eagg[mb * 16 + lg * 4 + r][lr] =
                    enc16(__builtin_bit_cast(unsigned short, (_Float16)val));
            }
    }
    __syncthreads();

    // all threads: pack pairs -> hpk, zero aenc (2 words per thread, coalesced)
    #pragma unroll
    for (int q = 0; q < 2; ++q) {
        int wd = t * 2 + q;
        int node = wd >> 3, p = wd & 7;
        int gn = base + node;
        if (gn < N_NODES) {
            unsigned lo = eagg[node][2 * p], hi = eagg[node][2 * p + 1];
            unsigned word = lo | (hi << 16);
            size_t idx = (size_t)gn * 8 + p;
            hpk[idx] = word;
            aenc[idx] = 0u;
        }
    }

    // bias + pack h to f16, NT store (keeps hpk/aenc L2-resident for k_edge)
    float bnc[4];
    #pragma unroll
    for (int nb = 0; nb < 4; ++nb) bnc[nb] = b_node[w * 64 + nb * 16 + lr];
    half8 hv8[8];
    #pragma unroll
    for (int mb = 0; mb < 4; ++mb)
        #pragma unroll
        for (int nb = 0; nb < 4; ++nb)
            #pragma unroll
            for (int r = 0; r < 4; ++r) {
                int idx = mb * 16 + nb * 4 + r;
                hv8[idx >> 3][idx & 7] = (_Float16)(acc[mb][nb][r] + bnc[nb]);
            }
    char* hb = (char*)hbuf + ((size_t)blockIdx.x * 256 + t) * 128;
    #pragma unroll
    for (int i = 0; i < 8; ++i)
        __builtin_nontemporal_store(hv8[i], (half8*)hb + i);
}

// Kernel 2: segment max. 8 threads/edge; packed u32 pair; pre-check + CAS.
// (Exactly the R4 form: proven 169 us / FETCH 236 MB / WRITE 142 MB.)
__global__ __launch_bounds__(256) void k_edge(
    const int* __restrict__ src, const int* __restrict__ dst,
    const unsigned* __restrict__ hpk, unsigned* __restrict__ aenc)
{
    int tid = blockIdx.x * 256 + threadIdx.x;
    int e = tid >> 3, p = tid & 7;
    int s = src[e], d = dst[e];
    unsigned mine = hpk[(size_t)s * 8 + p];
    unsigned* addr = aenc + (size_t)d * 8 + p;

    unsigned cur = *addr;
    unsigned lo = umax32(cur & 0xFFFFu, mine & 0xFFFFu);
    unsigned hi = umax32(cur >> 16, mine >> 16);
    unsigned nv = lo | (hi << 16);
    while (nv != cur) {
        unsigned old = atomicCAS(addr, cur, nv);
        if (old == cur) break;
        cur = old;
        lo = umax32(cur & 0xFFFFu, mine & 0xFFFFu);
        hi = umax32(cur >> 16, mine >> 16);
        nv = lo | (hi << 16);
    }
}

// K3 (epilogue): load packed h, neighbour MFMA from aenc, l2-normalize, store.
__global__ __launch_bounds__(256) void k_epi(
    const unsigned* __restrict__ aenc, const _Float16* __restrict__ Wnp,
    const float* __restrict__ b_neigh, const _Float16* __restrict__ hbuf,
    float* __restrict__ out)
{
    __shared__ _Float16 aggL[64][40];
    __shared__ float ss[4][64];
    __shared__ float invl[64];

    int t = threadIdx.x;
    int w = t >> 6, l = t & 63, lr = l & 15, lg = l >> 4;
    int tile = blockIdx.x;
    int base = tile * 64;

    // stage + decode agg tile
    for (int i = t; i < 64 * 8; i += 256) {
        int nl = i >> 3, p = i & 7;
        int gn = base + nl;
        unsigned v = (gn < N_NODES) ? aenc[(size_t)gn * 8 + p] : 0u;
        aggL[nl][2 * p]     = dec16((unsigned short)(v & 0xFFFFu));
        aggL[nl][2 * p + 1] = dec16((unsigned short)(v >> 16));
    }
    for (int i = t; i < 64 * 16; i += 256)
        aggL[i >> 4][16 + (i & 15)] = (_Float16)0.f;

    // this thread's packed h (written by k_gemm thread t of same tile)
    const char* hb = (const char*)hbuf + ((size_t)tile * 256 + t) * 128;
    half8 hv8[8];
    #pragma unroll
    for (int i = 0; i < 8; ++i)
        hv8[i] = __builtin_nontemporal_load((const half8*)hb + i);

    __syncthreads();

    // neighbour layer: one MFMA per (mb,nb), K=32 (upper 16 zero-padded)
    f32x4 nacc[4][4];
    {
        half8 an[4], bn[4];
        #pragma unroll
        for (int mb = 0; mb < 4; ++mb)
            an[mb] = *(const half8*)(&aggL[mb * 16 + lr][lg * 8]);
        #pragma unroll
        for (int nb = 0; nb < 4; ++nb)
            bn[nb] = ((const half8*)Wnp)[(w * 4 + nb) * 64 + l];
        f32x4 z = (f32x4){0.f, 0.f, 0.f, 0.f};
        #pragma unroll
        for (int mb = 0; mb < 4; ++mb)
            #pragma unroll
            for (int nb = 0; nb < 4; ++nb)
                nacc[mb][nb] = __builtin_amdgcn_mfma_f32_16x16x32_f16(
                    an[mb], bn[nb], z, 0, 0, 0);
    }

    float bec[4];
    #pragma unroll
    for (int nb = 0; nb < 4; ++nb) bec[nb] = b_neigh[w * 64 + nb * 16 + lr];
    #pragma unroll
    for (int mb = 0; mb < 4; ++mb)
        #pragma unroll
        for (int nb = 0; nb < 4; ++nb)
            #pragma unroll
            for (int r = 0; r < 4; ++r)
                nacc[mb][nb][r] += bec[nb];

    // sum of squares per node row
    #pragma unroll
    for (int mb = 0; mb < 4; ++mb) {
        float p[4] = {0.f, 0.f, 0.f, 0.f};
        #pragma unroll
        for (int nb = 0; nb < 4; ++nb)
            #pragma unroll
            for (int r = 0; r < 4; ++r) {
                int idx = mb * 16 + nb * 4 + r;
                float hf = (float)hv8[idx >> 3][idx & 7];
                p[r] += hf * hf + nacc[mb][nb][r] * nacc[mb][nb][r];
            }
        #pragma unroll
        for (int r = 0; r < 4; ++r) {
            float v = p[r];
            v += __shfl_xor(v, 1);
            v += __shfl_xor(v, 2);
            v += __shfl_xor(v, 4);
            v += __shfl_xor(v, 8);
            if (lr == 0) ss[w][mb * 16 + lg * 4 + r] = v;
        }
    }
    __syncthreads();
    if (t < 64) {
        float sq = ss[0][t] + ss[1][t] + ss[2][t] + ss[3][t];
        invl[t] = rsqrtf(fmaxf(sq, 1e-12f));
    }
    __syncthreads();

    #pragma unroll
    for (int mb = 0; mb < 4; ++mb)
        #pragma unroll
        for (int r = 0; r < 4; ++r) {
            int slot = mb * 16 + lg * 4 + r;
            int node = base + slot;
            if (node < N_NODES) {
                float inv = invl[slot];
                size_t row = (size_t)node * (2 * OUT);
                #pragma unroll
                for (int nb = 0; nb < 4; ++nb) {
                    int col = w * 64 + nb * 16 + lr;
                    int idx = mb * 16 + nb * 4 + r;
                    out[row + col] = (float)hv8[idx >> 3][idx & 7] * inv;
                    out[row + OUT + col] = nacc[mb][nb][r] * inv;
                }
            }
        }
}

extern "C" void kernel_launch(void* const* d_in, const int* in_sizes, int n_in,
                              void* d_out, int out_size, void* d_ws, size_t ws_size,
                              hipStream_t stream) {
    const float* x       = (const float*)d_in[0];
    const int*   src     = (const int*)d_in[1];
    const int*   dst     = (const int*)d_in[2];
    const float* W_node  = (const float*)d_in[3];
    const float* b_node  = (const float*)d_in[4];
    const float* W_agg   = (const float*)d_in[5];
    const float* b_agg   = (const float*)d_in[6];
    const float* W_neigh = (const float*)d_in[7];
    const float* b_neigh = (const float*)d_in[8];
    float* out = (float*)d_out;

    char* ws = (char*)d_ws;
    unsigned*  hpk  = (unsigned*)ws;      ws += (size_t)N_NODES * 8 * 4;
    unsigned*  aenc = (unsigned*)ws;      ws += (size_t)N_NODES * 8 * 4;
    _Float16*  Wp   = (_Float16*)ws;      ws += (size_t)16 * 8 * 64 * 8 * 2;
    _Float16*  Wnp  = (_Float16*)ws;      ws += (size_t)16 * 64 * 8 * 2;
    _Float16*  Wap  = (_Float16*)ws;      ws += (size_t)8 * 64 * 8 * 2;
    _Float16*  hbuf = (_Float16*)ws;      // N_TILES * 256 threads * 128 B = 51.2 MB

    k_pack<<<38, 256, 0, stream>>>(W_node, W_neigh, W_agg, Wp, Wnp, Wap);

    k_gemm<<<N_TILES, 256, 0, stream>>>(x, Wp, Wap, b_node, b_agg, hpk, aenc, hbuf);

    int g2 = (N_EDGES * 8) / 256;        // 100000
    k_edge<<<g2, 256, 0, stream>>>(src, dst, hpk, aenc);

    k_epi<<<N_TILES, 256, 0, stream>>>(aenc, Wnp, b_neigh, hbuf, out);
}

// Round 7
// 336.472 us; speedup vs baseline: 1.3680x; 1.2471x over previous
//
#include <hip/hip_runtime.h>

#define N_NODES 100000
#define N_EDGES 3200000
#define D_FEAT 256
#define HIDDEN 16
#define OUT 256
#define N_TILES 1563          // ceil(N_NODES/64)

typedef __attribute__((ext_vector_type(8))) _Float16 half8;
typedef __attribute__((ext_vector_type(4))) float f32x4;

__device__ __forceinline__ unsigned umax32(unsigned a, unsigned b) { return a > b ? a : b; }

// Monotone f16-bits <-> u16 mapping: encoded compare == float compare (no NaNs here).
__device__ __forceinline__ unsigned short enc16(unsigned short u) {
    return (u & 0x8000) ? (unsigned short)~u : (unsigned short)(u | 0x8000);
}
__device__ __forceinline__ _Float16 dec16(unsigned short e) {
    if (e == 0) return (_Float16)0.f;   // sentinel: no in-edge -> 0
    unsigned short b = (e & 0x8000) ? (unsigned short)(e & 0x7FFF) : (unsigned short)~e;
    return __builtin_bit_cast(_Float16, b);
}

// Pack W_node, W_neigh, W_agg into MFMA B-fragment layout (f16). 38 blocks.
__global__ void k_pack(const float* __restrict__ Wn, const float* __restrict__ Wng,
                       const float* __restrict__ Wag,
                       _Float16* __restrict__ Wp, _Float16* __restrict__ Wnp,
                       _Float16* __restrict__ Wap)
{
    int id = blockIdx.x * 256 + threadIdx.x;
    if (id < 8192) {                       // W_node: 16 nb x 8 kb x 64 lanes
        int l = id & 63, kb = (id >> 6) & 7, nb = id >> 9;
        int col = nb * 16 + (l & 15);
        int k0 = kb * 32 + (l >> 4) * 8;
        half8 v;
        #pragma unroll
        for (int j = 0; j < 8; ++j) v[j] = (_Float16)Wn[(size_t)(k0 + j) * OUT + col];
        ((half8*)Wp)[id] = v;
    } else if (id < 9216) {                // W_neigh: 16 nb x 64 lanes (K=32, zero-pad)
        int id2 = id - 8192;
        int l = id2 & 63, nb = id2 >> 6;
        int col = nb * 16 + (l & 15);
        int k0 = (l >> 4) * 8;
        half8 v;
        #pragma unroll
        for (int j = 0; j < 8; ++j) {
            int k = k0 + j;
            v[j] = (k < HIDDEN) ? (_Float16)Wng[(size_t)k * OUT + col] : (_Float16)0.f;
        }
        ((half8*)Wnp)[id2] = v;
    } else if (id < 9728) {                // W_agg: 1 nb (16 cols) x 8 kb x 64 lanes
        int id3 = id - 9216;
        int l = id3 & 63, kb = id3 >> 6;
        int col = l & 15;
        int k0 = kb * 32 + (l >> 4) * 8;
        half8 v;
        #pragma unroll
        for (int j = 0; j < 8; ++j) v[j] = (_Float16)Wag[(size_t)(k0 + j) * HIDDEN + col];
        ((half8*)Wap)[id3] = v;
    }
}

// K1: per 64-node tile, MFMA h = x@W_node (+bias, ->packed f16 hbuf) AND
// h_agg = x@W_agg (wave 0; +bias, encode -> hpk, zero aenc). x read once, f32,
// converted to f16 in registers. Normal (through-L2) stores only.
__global__ __launch_bounds__(256) void k_gemm(
    const float* __restrict__ x, const _Float16* __restrict__ Wp,
    const _Float16* __restrict__ Wap, const float* __restrict__ b_node,
    const float* __restrict__ b_agg, unsigned* __restrict__ hpk,
    unsigned* __restrict__ aenc, _Float16* __restrict__ hbuf)
{
    __shared__ unsigned short eagg[64][18];

    int t = threadIdx.x;
    int w = t >> 6, l = t & 63, lr = l & 15, lg = l >> 4;
    int base = blockIdx.x * 64;

    size_t arow[4];
    #pragma unroll
    for (int mb = 0; mb < 4; ++mb) {
        int node = base + mb * 16 + lr;
        if (node > N_NODES - 1) node = N_NODES - 1;
        arow[mb] = (size_t)node * D_FEAT + lg * 8;
    }

    f32x4 acc[4][4];
    #pragma unroll
    for (int mb = 0; mb < 4; ++mb)
        #pragma unroll
        for (int nb = 0; nb < 4; ++nb) acc[mb][nb] = (f32x4){0.f, 0.f, 0.f, 0.f};
    f32x4 agga[4];
    #pragma unroll
    for (int mb = 0; mb < 4; ++mb) agga[mb] = (f32x4){0.f, 0.f, 0.f, 0.f};

    const half8* WpV = (const half8*)Wp;
    const half8* WaV = (const half8*)Wap;

    #pragma unroll
    for (int kb = 0; kb < 8; ++kb) {
        half8 a[4];
        #pragma unroll
        for (int mb = 0; mb < 4; ++mb) {
            const float4* p = (const float4*)(x + arow[mb] + kb * 32);
            float4 u = p[0], v = p[1];
            half8 h;
            h[0]=(_Float16)u.x; h[1]=(_Float16)u.y; h[2]=(_Float16)u.z; h[3]=(_Float16)u.w;
            h[4]=(_Float16)v.x; h[5]=(_Float16)v.y; h[6]=(_Float16)v.z; h[7]=(_Float16)v.w;
            a[mb] = h;
        }
        half8 b[4];
        #pragma unroll
        for (int nb = 0; nb < 4; ++nb)
            b[nb] = WpV[((w * 4 + nb) * 8 + kb) * 64 + l];
        if (w == 0) {
            half8 bg = WaV[kb * 64 + l];
            #pragma unroll
            for (int mb = 0; mb < 4; ++mb)
                agga[mb] = __builtin_amdgcn_mfma_f32_16x16x32_f16(a[mb], bg, agga[mb], 0, 0, 0);
        }
        #pragma unroll
        for (int mb = 0; mb < 4; ++mb)
            #pragma unroll
            for (int nb = 0; nb < 4; ++nb)
                acc[mb][nb] = __builtin_amdgcn_mfma_f32_16x16x32_f16(
                    a[mb], b[nb], acc[mb][nb], 0, 0, 0);
    }

    // wave 0: bias + encode h_agg into LDS (slot = node-in-tile, col = hidden idx)
    if (w == 0) {
        float ba = b_agg[lr];
        #pragma unroll
        for (int mb = 0; mb < 4; ++mb)
            #pragma unroll
            for (int r = 0; r < 4; ++r) {
                float val = agga[mb][r] + ba;
                eagg[mb * 16 + lg * 4 + r][lr] =
                    enc16(__builtin_bit_cast(unsigned short, (_Float16)val));
            }
    }
    __syncthreads();

    // all threads: pack pairs -> hpk, zero aenc (2 words per thread, coalesced)
    #pragma unroll
    for (int q = 0; q < 2; ++q) {
        int wd = t * 2 + q;
        int node = wd >> 3, p = wd & 7;
        int gn = base + node;
        if (gn < N_NODES) {
            unsigned lo = eagg[node][2 * p], hi = eagg[node][2 * p + 1];
            unsigned word = lo | (hi << 16);
            size_t idx = (size_t)gn * 8 + p;
            hpk[idx] = word;
            aenc[idx] = 0u;
        }
    }

    // bias + pack h to f16, normal store (128 B contiguous per thread)
    float bnc[4];
    #pragma unroll
    for (int nb = 0; nb < 4; ++nb) bnc[nb] = b_node[w * 64 + nb * 16 + lr];
    half8 hv8[8];
    #pragma unroll
    for (int mb = 0; mb < 4; ++mb)
        #pragma unroll
        for (int nb = 0; nb < 4; ++nb)
            #pragma unroll
            for (int r = 0; r < 4; ++r) {
                int idx = mb * 16 + nb * 4 + r;
                hv8[idx >> 3][idx & 7] = (_Float16)(acc[mb][nb][r] + bnc[nb]);
            }
    half8* hb = (half8*)((char*)hbuf + ((size_t)blockIdx.x * 256 + t) * 128);
    #pragma unroll
    for (int i = 0; i < 8; ++i)
        hb[i] = hv8[i];
}

// Kernel 2: segment max. 8 threads/edge; packed u32 pair; pre-check + CAS.
// (Exactly the R4 form: proven 169 us / FETCH 236 MB / WRITE 142 MB.)
__global__ __launch_bounds__(256) void k_edge(
    const int* __restrict__ src, const int* __restrict__ dst,
    const unsigned* __restrict__ hpk, unsigned* __restrict__ aenc)
{
    int tid = blockIdx.x * 256 + threadIdx.x;
    int e = tid >> 3, p = tid & 7;
    int s = src[e], d = dst[e];
    unsigned mine = hpk[(size_t)s * 8 + p];
    unsigned* addr = aenc + (size_t)d * 8 + p;

    unsigned cur = *addr;
    unsigned lo = umax32(cur & 0xFFFFu, mine & 0xFFFFu);
    unsigned hi = umax32(cur >> 16, mine >> 16);
    unsigned nv = lo | (hi << 16);
    while (nv != cur) {
        unsigned old = atomicCAS(addr, cur, nv);
        if (old == cur) break;
        cur = old;
        lo = umax32(cur & 0xFFFFu, mine & 0xFFFFu);
        hi = umax32(cur >> 16, mine >> 16);
        nv = lo | (hi << 16);
    }
}

// K3 (epilogue): load packed h, neighbour MFMA from aenc, l2-normalize, store.
__global__ __launch_bounds__(256) void k_epi(
    const unsigned* __restrict__ aenc, const _Float16* __restrict__ Wnp,
    const float* __restrict__ b_neigh, const _Float16* __restrict__ hbuf,
    float* __restrict__ out)
{
    __shared__ _Float16 aggL[64][40];
    __shared__ float ss[4][64];
    __shared__ float invl[64];

    int t = threadIdx.x;
    int w = t >> 6, l = t & 63, lr = l & 15, lg = l >> 4;
    int tile = blockIdx.x;
    int base = tile * 64;

    // stage + decode agg tile
    for (int i = t; i < 64 * 8; i += 256) {
        int nl = i >> 3, p = i & 7;
        int gn = base + nl;
        unsigned v = (gn < N_NODES) ? aenc[(size_t)gn * 8 + p] : 0u;
        aggL[nl][2 * p]     = dec16((unsigned short)(v & 0xFFFFu));
        aggL[nl][2 * p + 1] = dec16((unsigned short)(v >> 16));
    }
    for (int i = t; i < 64 * 16; i += 256)
        aggL[i >> 4][16 + (i & 15)] = (_Float16)0.f;

    // this thread's packed h (written by k_gemm thread t of same tile)
    const half8* hb = (const half8*)((const char*)hbuf + ((size_t)tile * 256 + t) * 128);
    half8 hv8[8];
    #pragma unroll
    for (int i = 0; i < 8; ++i)
        hv8[i] = hb[i];

    __syncthreads();

    // neighbour layer: one MFMA per (mb,nb), K=32 (upper 16 zero-padded)
    f32x4 nacc[4][4];
    {
        half8 an[4], bn[4];
        #pragma unroll
        for (int mb = 0; mb < 4; ++mb)
            an[mb] = *(const half8*)(&aggL[mb * 16 + lr][lg * 8]);
        #pragma unroll
        for (int nb = 0; nb < 4; ++nb)
            bn[nb] = ((const half8*)Wnp)[(w * 4 + nb) * 64 + l];
        f32x4 z = (f32x4){0.f, 0.f, 0.f, 0.f};
        #pragma unroll
        for (int mb = 0; mb < 4; ++mb)
            #pragma unroll
            for (int nb = 0; nb < 4; ++nb)
                nacc[mb][nb] = __builtin_amdgcn_mfma_f32_16x16x32_f16(
                    an[mb], bn[nb], z, 0, 0, 0);
    }

    float bec[4];
    #pragma unroll
    for (int nb = 0; nb < 4; ++nb) bec[nb] = b_neigh[w * 64 + nb * 16 + lr];
    #pragma unroll
    for (int mb = 0; mb < 4; ++mb)
        #pragma unroll
        for (int nb = 0; nb < 4; ++nb)
            #pragma unroll
            for (int r = 0; r < 4; ++r)
                nacc[mb][nb][r] += bec[nb];

    // sum of squares per node row
    #pragma unroll
    for (int mb = 0; mb < 4; ++mb) {
        float p[4] = {0.f, 0.f, 0.f, 0.f};
        #pragma unroll
        for (int nb = 0; nb < 4; ++nb)
            #pragma unroll
            for (int r = 0; r < 4; ++r) {
                int idx = mb * 16 + nb * 4 + r;
                float hf = (float)hv8[idx >> 3][idx & 7];
                p[r] += hf * hf + nacc[mb][nb][r] * nacc[mb][nb][r];
            }
        #pragma unroll
        for (int r = 0; r < 4; ++r) {
            float v = p[r];
            v += __shfl_xor(v, 1);
            v += __shfl_xor(v, 2);
            v += __shfl_xor(v, 4);
            v += __shfl_xor(v, 8);
            if (lr == 0) ss[w][mb * 16 + lg * 4 + r] = v;
        }
    }
    __syncthreads();
    if (t < 64) {
        float sq = ss[0][t] + ss[1][t] + ss[2][t] + ss[3][t];
        invl[t] = rsqrtf(fmaxf(sq, 1e-12f));
    }
    __syncthreads();

    #pragma unroll
    for (int mb = 0; mb < 4; ++mb)
        #pragma unroll
        for (int r = 0; r < 4; ++r) {
            int slot = mb * 16 + lg * 4 + r;
            int node = base + slot;
            if (node < N_NODES) {
                float inv = invl[slot];
                size_t row = (size_t)node * (2 * OUT);
                #pragma unroll
                for (int nb = 0; nb < 4; ++nb) {
                    int col = w * 64 + nb * 16 + lr;
                    int idx = mb * 16 + nb * 4 + r;
                    out[row + col] = (float)hv8[idx >> 3][idx & 7] * inv;
                    out[row + OUT + col] = nacc[mb][nb][r] * inv;
                }
            }
        }
}

extern "C" void kernel_launch(void* const* d_in, const int* in_sizes, int n_in,
                              void* d_out, int out_size, void* d_ws, size_t ws_size,
                              hipStream_t stream) {
    const float* x       = (const float*)d_in[0];
    const int*   src     = (const int*)d_in[1];
    const int*   dst     = (const int*)d_in[2];
    const float* W_node  = (const float*)d_in[3];
    const float* b_node  = (const float*)d_in[4];
    const float* W_agg   = (const float*)d_in[5];
    const float* b_agg   = (const float*)d_in[6];
    const float* W_neigh = (const float*)d_in[7];
    const float* b_neigh = (const float*)d_in[8];
    float* out = (float*)d_out;

    char* ws = (char*)d_ws;
    unsigned*  hpk  = (unsigned*)ws;      ws += (size_t)N_NODES * 8 * 4;
    unsigned*  aenc = (unsigned*)ws;      ws += (size_t)N_NODES * 8 * 4;
    _Float16*  Wp   = (_Float16*)ws;      ws += (size_t)16 * 8 * 64 * 8 * 2;
    _Float16*  Wnp  = (_Float16*)ws;      ws += (size_t)16 * 64 * 8 * 2;
    _Float16*  Wap  = (_Float16*)ws;      ws += (size_t)8 * 64 * 8 * 2;
    _Float16*  hbuf = (_Float16*)ws;      // N_TILES * 256 threads * 128 B = 51.2 MB

    k_pack<<<38, 256, 0, stream>>>(W_node, W_neigh, W_agg, Wp, Wnp, Wap);

    k_gemm<<<N_TILES, 256, 0, stream>>>(x, Wp, Wap, b_node, b_agg, hpk, aenc, hbuf);

    int g2 = (N_EDGES * 8) / 256;        // 100000
    k_edge<<<g2, 256, 0, stream>>>(src, dst, hpk, aenc);

    k_epi<<<N_TILES, 256, 0, stream>>>(aenc, Wnp, b_neigh, hbuf, out);
}